// Round 12
// baseline (3687.975 us; speedup 1.0000x reference)
//
#include <hip/hip_runtime.h>
#include <math.h>

#define BATCH 4096
#define NIN   4096
#define NOUT  4096

#define BM 128
#define BN 64
#define BK 32
#define NSTAGE (NIN / BK)        // 128
// R9-verified ORDER (frozen): [512x8] k-panels, single ascending fmaf chain,
// fold every 16 stages (16*32 = 512), f32 epilogue. Do not touch.

__device__ __forceinline__ float2 compute_terms(float xv) {
    float h  = (float)exp10(-(double)xv);
    float oh = 1e-14f / h;
    return make_float2(h * 0.1f, oh * 0.1f);
}

__global__ __launch_bounds__(256) void precompute_terms(const float* __restrict__ x,
                                                        float2* __restrict__ a2, int n) {
    int stride = gridDim.x * blockDim.x;
    for (int i = blockIdx.x * blockDim.x + threadIdx.x; i < n; i += stride)
        a2[i] = compute_terms(x[i]);
}

__device__ __forceinline__ float signf_of(float wv) {
    return (wv > 0.f) ? 1.f : ((wv < 0.f) ? -1.f : 0.f);
}

// R11 + two fixes:
//  (a) As pad +1 -> +2 float2: row stride 1040 B = 65*16 -> EVERY row 16B-aligned
//      -> the 8 consecutive av float2 reads fuse to 4x ds_read_b128 (R11's 1032 B
//      rows broke alignment on odd k -> b64 fallback = 2x DS instrs + addr VALU).
//      Bank rotation across k preserved: row base bank = (4k)%32.
//  (b) launch_bounds min-waves 2 -> 3: VGPR 116 and LDS 41.7 KB both fit
//      3 blocks/CU (12 waves) -> fills the measured 35% idle.
__global__ __launch_bounds__(256, 3) void acid_gemm_t14(const float2* __restrict__ A2,
                                                        const float* __restrict__ W,
                                                        float* __restrict__ out) {
    __shared__ float2 As[BK][BM + 2];   // [32][130] f2 = 33280 B, rows 16B-aligned
    __shared__ float  Bs[BK][BN];       // [32][64]  f32 = 8192 B

    const int tid = threadIdx.x;
    const int tx  = tid & 15;     // cols tx*4..+3
    const int ty  = tid >> 4;     // rows ty*8..+7
    const int bm0 = blockIdx.y * BM;
    const int bn0 = blockIdx.x * BN;

    // A staging: thread covers rows m0+16r (r=0..7), f4-col ac (k = 2*ac, 2*ac+1)
    const int m0 = tid >> 4;      // 0..15
    const int ac = tid & 15;      // f4 col within 32-k tile
    // W staging: thread covers k rows kw0+16r (r=0..1), f4-col wc (cols 4*wc..+3)
    const int kw0 = tid >> 4;
    const int wc  = tid & 15;

    float ma[8][4] = {}, mb[8][4] = {};   // C accs (panel-folded)
    float ca[8][4] = {}, cb[8][4] = {};   // in-panel ascending-k chains
    float4 areg[8], wreg[2];

    #define ISSUE_LOADS(s)                                                          \
        {                                                                           \
            const int k0_ = (s) * BK;                                               \
            _Pragma("unroll")                                                       \
            for (int r = 0; r < 8; ++r) {                                           \
                const float4* p = (const float4*)(A2 +                              \
                    (size_t)(bm0 + m0 + 16 * r) * NIN + k0_);                       \
                areg[r] = p[ac];                                                    \
            }                                                                       \
            _Pragma("unroll")                                                       \
            for (int r = 0; r < 2; ++r) {                                           \
                const float4* p = (const float4*)(W +                               \
                    (size_t)(k0_ + kw0 + 16 * r) * NOUT + bn0);                     \
                wreg[r] = p[wc];                                                    \
            }                                                                       \
        }

    #define WRITE_LDS()                                                             \
        {                                                                           \
            _Pragma("unroll")                                                       \
            for (int r = 0; r < 8; ++r) {                                           \
                int m = m0 + 16 * r;                                                \
                As[2 * ac][m]     = make_float2(areg[r].x, areg[r].y);              \
                As[2 * ac + 1][m] = make_float2(areg[r].z, areg[r].w);              \
            }                                                                       \
            _Pragma("unroll")                                                       \
            for (int r = 0; r < 2; ++r) {                                           \
                int k = kw0 + 16 * r;                                               \
                float4 wv = wreg[r];                                                \
                *(float4*)&Bs[k][4 * wc] = make_float4(                             \
                    signf_of(wv.x), signf_of(wv.y), signf_of(wv.z), signf_of(wv.w));\
            }                                                                       \
        }

    // prologue: stage 0
    ISSUE_LOADS(0);
    WRITE_LDS();
    __syncthreads();

    for (int s = 0; s < NSTAGE; ++s) {
        if (s + 1 < NSTAGE) ISSUE_LOADS(s + 1);   // in flight across the compute

        // compute: 32 ascending k, chain order identical to R9 (bit-exact)
        #pragma unroll 8
        for (int k = 0; k < BK; ++k) {
            float2 av[8];
            float  sv[4];
            #pragma unroll
            for (int m = 0; m < 8; ++m) av[m] = As[k][ty * 8 + m];
            #pragma unroll
            for (int n = 0; n < 4; ++n) sv[n] = Bs[k][tx * 4 + n];
            #pragma unroll
            for (int m = 0; m < 8; ++m)
                #pragma unroll
                for (int n = 0; n < 4; ++n) {
                    ca[m][n] = fmaf(av[m].x, sv[n], ca[m][n]);
                    cb[m][n] = fmaf(av[m].y, sv[n], cb[m][n]);
                }
        }

        // panel boundary every 512 k: C += panel_acc (one f32 add)
        if (((s + 1) & 15) == 0) {
            #pragma unroll
            for (int m = 0; m < 8; ++m)
                #pragma unroll
                for (int n = 0; n < 4; ++n) {
                    ma[m][n] += ca[m][n]; ca[m][n] = 0.f;
                    mb[m][n] += cb[m][n]; cb[m][n] = 0.f;
                }
        }

        __syncthreads();                       // all waves done READING As/Bs
        if (s + 1 < NSTAGE) WRITE_LDS();       // cheap reg->LDS (loads long done)
        __syncthreads();                       // tile ready
    }

    // np f32 epilogue (frozen)
    #pragma unroll
    for (int m = 0; m < 8; ++m) {
        int row = bm0 + ty * 8 + m;
        #pragma unroll
        for (int n = 0; n < 4; ++n) {
            int col = bn0 + tx * 4 + n;
            float r    = ma[m][n] - mb[m][n];
            float conc = fabsf(r) / 409.6f;
            float hc   = (r < 0.f) ? (1e-14f / conc) : conc;
            float ph   = (-logf(hc)) / 2.302585092994046f;
            out[(size_t)row * NOUT + col] = ph;
        }
    }
    #undef ISSUE_LOADS
    #undef WRITE_LDS
}

// Fallback (ws too small): R9's proven kernel with on-the-fly terms.
__global__ __launch_bounds__(256, 2) void acid_gemm_fly(const float* __restrict__ X,
                                                        const float* __restrict__ W,
                                                        float* __restrict__ out) {
    __shared__ float2 Asf[BK][BM + 2];
    __shared__ float  Bsf[BK][BN];
    const int tid = threadIdx.x;
    const int tx = tid & 15, ty = tid >> 4;
    const int bm0 = blockIdx.y * BM, bn0 = blockIdx.x * BN;
    float ma[8][4] = {}, mb[8][4] = {}, ca[8][4] = {}, cb[8][4] = {};
    for (int s = 0; s < NSTAGE; ++s) {
        const int k0 = s * BK;
        for (int idx = tid; idx < BM * BK; idx += 256) {
            int m = idx >> 5, k = idx & 31;
            Asf[k][m] = compute_terms(X[(size_t)(bm0 + m) * NIN + k0 + k]);
        }
        for (int idx = tid; idx < BK * BN; idx += 256) {
            int k = idx >> 6, c = idx & 63;
            Bsf[k][c] = signf_of(W[(size_t)(k0 + k) * NOUT + bn0 + c]);
        }
        __syncthreads();
        #pragma unroll 4
        for (int k = 0; k < BK; ++k) {
            float2 av[8]; float sv[4];
            #pragma unroll
            for (int m = 0; m < 8; ++m) av[m] = Asf[k][ty * 8 + m];
            #pragma unroll
            for (int n = 0; n < 4; ++n) sv[n] = Bsf[k][tx * 4 + n];
            #pragma unroll
            for (int m = 0; m < 8; ++m)
                #pragma unroll
                for (int n = 0; n < 4; ++n) {
                    ca[m][n] = fmaf(av[m].x, sv[n], ca[m][n]);
                    cb[m][n] = fmaf(av[m].y, sv[n], cb[m][n]);
                }
        }
        if (((s + 1) & 15) == 0) {
            #pragma unroll
            for (int m = 0; m < 8; ++m)
                #pragma unroll
                for (int n = 0; n < 4; ++n) {
                    ma[m][n] += ca[m][n]; ca[m][n] = 0.f;
                    mb[m][n] += cb[m][n]; cb[m][n] = 0.f;
                }
        }
        __syncthreads();
    }
    #pragma unroll
    for (int m = 0; m < 8; ++m) {
        int row = bm0 + ty * 8 + m;
        #pragma unroll
        for (int n = 0; n < 4; ++n) {
            int col = bn0 + tx * 4 + n;
            float r = ma[m][n] - mb[m][n];
            float conc = fabsf(r) / 409.6f;
            float hc = (r < 0.f) ? (1e-14f / conc) : conc;
            out[(size_t)row * NOUT + col] = (-logf(hc)) / 2.302585092994046f;
        }
    }
}

extern "C" void kernel_launch(void* const* d_in, const int* in_sizes, int n_in,
                              void* d_out, int out_size, void* d_ws, size_t ws_size,
                              hipStream_t stream) {
    const float* x = (const float*)d_in[0];
    const float* w = (const float*)d_in[1];
    float* out = (float*)d_out;

    const size_t needA = (size_t)BATCH * NIN * sizeof(float2);  // 134.2 MB
    dim3 grid(NOUT / BN, BATCH / BM);

    if (ws_size >= needA) {
        float2* a2 = (float2*)d_ws;
        precompute_terms<<<4096, 256, 0, stream>>>(x, a2, BATCH * NIN);
        acid_gemm_t14<<<grid, dim3(256), 0, stream>>>(a2, w, out);
    } else {
        acid_gemm_fly<<<grid, dim3(256), 0, stream>>>(x, w, out);
    }
}

// Round 13
// 2241.663 us; speedup vs baseline: 1.6452x; 1.6452x over previous
//
#include <hip/hip_runtime.h>
#include <math.h>

#define BATCH 4096
#define NIN   4096
#define NOUT  4096

#define BM 128
#define BN 64
#define BK 32
#define NSTAGE (NIN / BK)        // 128
// R9-verified ACID ORDER (frozen): [512x8] k-panels, single ascending fmaf
// chain, fold every 16 stages, f32 epilogue. BASE is order-insensitive
// (terms ~1e-15, any-order noise ~1e-18 << 1.12e-13 critical scale) ->
// computed on the MFMA pipe in bf16 (exact +-1 signs, f32 accumulate).

typedef __attribute__((ext_vector_type(8))) short bf16x8;
typedef __attribute__((ext_vector_type(4))) float f32x4;
typedef __attribute__((ext_vector_type(8))) unsigned short u16x8;

__device__ __forceinline__ float2 compute_terms(float xv) {
    float h  = (float)exp10(-(double)xv);
    float oh = 1e-14f / h;
    return make_float2(h * 0.1f, oh * 0.1f);
}

__device__ __forceinline__ unsigned short bf16_rne(float v) {
    unsigned int b = __float_as_uint(v);
    return (unsigned short)((b + 0x7FFFu + ((b >> 16) & 1u)) >> 16);
}

// planar outputs: a_acid f32 [B*K], a_b16 bf16 [B*K] (base terms)
__global__ __launch_bounds__(256) void precompute_terms2(const float* __restrict__ x,
                                                         float* __restrict__ a_acid,
                                                         unsigned short* __restrict__ a_b16,
                                                         int n) {
    int stride = gridDim.x * blockDim.x;
    for (int i = blockIdx.x * blockDim.x + threadIdx.x; i < n; i += stride) {
        float2 t = compute_terms(x[i]);
        a_acid[i] = t.x;
        a_b16[i]  = bf16_rne(t.y);
    }
}

__device__ __forceinline__ float signf_of(float wv) {
    return (wv > 0.f) ? 1.f : ((wv < 0.f) ? -1.f : 0.f);
}
__device__ __forceinline__ unsigned short signbf16_of(float wv) {
    return (wv > 0.f) ? 0x3F80u : ((wv < 0.f) ? 0xBF80u : 0u);
}

// LDS plan (union, 40960 B):
//   As_acid [32][132] f32  @0      (16896)  acid A, [k][m], row 528B 16B-aligned
//   Bs      [32][68]  f32  @16896  (8704)   sign(W) f32 for acid VALU
//   baseA   [128][40] u16  @25600  (10240)  base A bf16, [m][k], row 80B
//   Bt      [64][40]  u16  @35840  (5120)   sign(W) bf16 TRANSPOSED [col][k]
//   Bout    [128][68] f32  @0      (34816)  base result (post-loop reuse)
#define OFF_BS    16896
#define OFF_BA    25600
#define OFF_BT    35840

__global__ __launch_bounds__(256, 2) void acid_gemm_hyb(const float* __restrict__ Aa,
                                                        const unsigned short* __restrict__ Ab,
                                                        const float* __restrict__ W,
                                                        float* __restrict__ out) {
    __shared__ __align__(16) char smem[40960];
    float*          As_acid = (float*)smem;                   // [k*132 + m]
    float*          Bs      = (float*)(smem + OFF_BS);        // [k*68 + c]
    unsigned short* baseA   = (unsigned short*)(smem + OFF_BA); // [m*40 + k]
    unsigned short* Bt      = (unsigned short*)(smem + OFF_BT); // [c*40 + k]
    float*          Bout    = (float*)smem;                   // [m*68 + c]

    const int tid  = threadIdx.x;
    const int tx   = tid & 15;     // acid cols tx*4..+3
    const int ty   = tid >> 4;     // acid rows ty*8..+7
    const int lane = tid & 63;
    const int wv   = tid >> 6;     // wave 0..3 -> base rows wv*32..+31
    const int g    = lane >> 4;    // frag k-group
    const int r16  = lane & 15;
    const int bm0  = blockIdx.y * BM;
    const int bn0  = blockIdx.x * BN;

    float ma[8][4] = {}, ca[8][4] = {};   // acid: panel-folded C + in-panel chain
    f32x4 acc[2][4] = {};                 // base MFMA acc: [row-tile][col-tile]

    float4 areg[4];   // acid A stage: rows (tid>>3)+32r, f4-quad tid&7
    bf16x8 breg[2];   // base A stage: rows (tid>>2)+64r, u16x8-chunk tid&3
    float4 wreg[2];   // W stage: k rows (tid>>4)+16r, cols (tid&15)*4..+3

    #define ISSUE_LOADS(s)                                                         \
        {                                                                          \
            const int k0_ = (s) * BK;                                              \
            _Pragma("unroll")                                                      \
            for (int r = 0; r < 4; ++r)                                            \
                areg[r] = *(const float4*)(Aa +                                    \
                    (size_t)(bm0 + (tid >> 3) + 32 * r) * NIN + k0_ + (tid & 7) * 4);\
            _Pragma("unroll")                                                      \
            for (int r = 0; r < 2; ++r)                                            \
                breg[r] = *(const bf16x8*)(Ab +                                    \
                    (size_t)(bm0 + (tid >> 2) + 64 * r) * NIN + k0_ + (tid & 3) * 8);\
            _Pragma("unroll")                                                      \
            for (int r = 0; r < 2; ++r)                                            \
                wreg[r] = *(const float4*)(W +                                     \
                    (size_t)(k0_ + (tid >> 4) + 16 * r) * NOUT + bn0 + (tid & 15) * 4);\
        }

    #define WRITE_LDS()                                                            \
        {                                                                          \
            _Pragma("unroll")                                                      \
            for (int r = 0; r < 4; ++r) {                                          \
                int m_ = (tid >> 3) + 32 * r, q_ = (tid & 7) * 4;                  \
                As_acid[(q_ + 0) * 132 + m_] = areg[r].x;                          \
                As_acid[(q_ + 1) * 132 + m_] = areg[r].y;                          \
                As_acid[(q_ + 2) * 132 + m_] = areg[r].z;                          \
                As_acid[(q_ + 3) * 132 + m_] = areg[r].w;                          \
            }                                                                      \
            _Pragma("unroll")                                                      \
            for (int r = 0; r < 2; ++r)                                            \
                *(bf16x8*)&baseA[((tid >> 2) + 64 * r) * 40 + (tid & 3) * 8] = breg[r];\
            _Pragma("unroll")                                                      \
            for (int r = 0; r < 2; ++r) {                                          \
                float4 w_ = wreg[r];                                               \
                *(float4*)&Bs[((tid >> 4) + 16 * r) * 68 + (tid & 15) * 4] =       \
                    make_float4(signf_of(w_.x), signf_of(w_.y),                    \
                                signf_of(w_.z), signf_of(w_.w));                   \
                int kk_ = (tid >> 4) + 16 * r;                                     \
                Bt[((tid & 15) * 4 + 0) * 40 + kk_] = signbf16_of(w_.x);           \
                Bt[((tid & 15) * 4 + 1) * 40 + kk_] = signbf16_of(w_.y);           \
                Bt[((tid & 15) * 4 + 2) * 40 + kk_] = signbf16_of(w_.z);           \
                Bt[((tid & 15) * 4 + 3) * 40 + kk_] = signbf16_of(w_.w);           \
            }                                                                      \
        }

    ISSUE_LOADS(0);
    WRITE_LDS();
    __syncthreads();

    for (int s = 0; s < NSTAGE; ++s) {
        if (s + 1 < NSTAGE) ISSUE_LOADS(s + 1);   // T14: in flight across compute

        // ---- base GEMM on the matrix pipe (order-free, co-issues with VALU) ----
        // A-frag (16x32): lane holds A[r16][g*8+j]; B-frag (32x16): B[g*8+j][r16]
        {
            bf16x8 af0 = *(const bf16x8*)&baseA[(wv * 32 +      r16) * 40 + g * 8];
            bf16x8 af1 = *(const bf16x8*)&baseA[(wv * 32 + 16 + r16) * 40 + g * 8];
            #pragma unroll
            for (int tc = 0; tc < 4; ++tc) {
                bf16x8 bf = *(const bf16x8*)&Bt[(tc * 16 + r16) * 40 + g * 8];
                acc[0][tc] = __builtin_amdgcn_mfma_f32_16x16x32_bf16(af0, bf, acc[0][tc], 0, 0, 0);
                acc[1][tc] = __builtin_amdgcn_mfma_f32_16x16x32_bf16(af1, bf, acc[1][tc], 0, 0, 0);
            }
        }

        // ---- acid chain: 32 ascending k, bit-identical to R9/R11 ----
        #pragma unroll 8
        for (int k = 0; k < BK; ++k) {
            const float4 pa = *(const float4*)&As_acid[k * 132 + ty * 8];
            const float4 pb = *(const float4*)&As_acid[k * 132 + ty * 8 + 4];
            const float4 sv = *(const float4*)&Bs[k * 68 + tx * 4];
            const float av[8] = {pa.x, pa.y, pa.z, pa.w, pb.x, pb.y, pb.z, pb.w};
            const float sn[4] = {sv.x, sv.y, sv.z, sv.w};
            #pragma unroll
            for (int m = 0; m < 8; ++m)
                #pragma unroll
                for (int n = 0; n < 4; ++n)
                    ca[m][n] = fmaf(av[m], sn[n], ca[m][n]);
        }

        if (((s + 1) & 15) == 0) {     // panel fold every 512 k
            #pragma unroll
            for (int m = 0; m < 8; ++m)
                #pragma unroll
                for (int n = 0; n < 4; ++n) {
                    ma[m][n] += ca[m][n]; ca[m][n] = 0.f;
                }
        }

        __syncthreads();
        if (s + 1 < NSTAGE) WRITE_LDS();
        __syncthreads();
    }

    // ---- combine: base D-frags -> LDS, then per-thread epilogue ----
    #pragma unroll
    for (int tr = 0; tr < 2; ++tr)
        #pragma unroll
        for (int tc = 0; tc < 4; ++tc)
            #pragma unroll
            for (int rr = 0; rr < 4; ++rr)
                Bout[(wv * 32 + tr * 16 + g * 4 + rr) * 68 + tc * 16 + r16] = acc[tr][tc][rr];
    __syncthreads();

    #pragma unroll
    for (int m = 0; m < 8; ++m) {
        int row = ty * 8 + m;
        const float4 bv = *(const float4*)&Bout[row * 68 + tx * 4];
        const float bb[4] = {bv.x, bv.y, bv.z, bv.w};
        #pragma unroll
        for (int n = 0; n < 4; ++n) {
            float r    = ma[m][n] - bb[n];
            float conc = fabsf(r) / 409.6f;
            float hc   = (r < 0.f) ? (1e-14f / conc) : conc;
            float ph   = (-logf(hc)) / 2.302585092994046f;
            out[(size_t)(bm0 + row) * NOUT + bn0 + tx * 4 + n] = ph;
        }
    }
    #undef ISSUE_LOADS
    #undef WRITE_LDS
}

// Fallback (ws too small): R9's proven all-VALU kernel, on-the-fly terms.
__global__ __launch_bounds__(256, 2) void acid_gemm_fly(const float* __restrict__ X,
                                                        const float* __restrict__ W,
                                                        float* __restrict__ out) {
    __shared__ float2 Asf[BK][BM + 2];
    __shared__ float  Bsf[BK][BN];
    const int tid = threadIdx.x;
    const int tx = tid & 15, ty = tid >> 4;
    const int bm0 = blockIdx.y * BM, bn0 = blockIdx.x * BN;
    float ma[8][4] = {}, mb[8][4] = {}, ca[8][4] = {}, cb[8][4] = {};
    for (int s = 0; s < NSTAGE; ++s) {
        const int k0 = s * BK;
        for (int idx = tid; idx < BM * BK; idx += 256) {
            int m = idx >> 5, k = idx & 31;
            Asf[k][m] = compute_terms(X[(size_t)(bm0 + m) * NIN + k0 + k]);
        }
        for (int idx = tid; idx < BK * BN; idx += 256) {
            int k = idx >> 6, c = idx & 63;
            Bsf[k][c] = signf_of(W[(size_t)(k0 + k) * NOUT + bn0 + c]);
        }
        __syncthreads();
        #pragma unroll 4
        for (int k = 0; k < BK; ++k) {
            float2 av[8]; float sv[4];
            #pragma unroll
            for (int m = 0; m < 8; ++m) av[m] = Asf[k][ty * 8 + m];
            #pragma unroll
            for (int n = 0; n < 4; ++n) sv[n] = Bsf[k][tx * 4 + n];
            #pragma unroll
            for (int m = 0; m < 8; ++m)
                #pragma unroll
                for (int n = 0; n < 4; ++n) {
                    ca[m][n] = fmaf(av[m].x, sv[n], ca[m][n]);
                    cb[m][n] = fmaf(av[m].y, sv[n], cb[m][n]);
                }
        }
        if (((s + 1) & 15) == 0) {
            #pragma unroll
            for (int m = 0; m < 8; ++m)
                #pragma unroll
                for (int n = 0; n < 4; ++n) {
                    ma[m][n] += ca[m][n]; ca[m][n] = 0.f;
                    mb[m][n] += cb[m][n]; cb[m][n] = 0.f;
                }
        }
        __syncthreads();
    }
    #pragma unroll
    for (int m = 0; m < 8; ++m) {
        int row = bm0 + ty * 8 + m;
        #pragma unroll
        for (int n = 0; n < 4; ++n) {
            int col = bn0 + tx * 4 + n;
            float r = ma[m][n] - mb[m][n];
            float conc = fabsf(r) / 409.6f;
            float hc = (r < 0.f) ? (1e-14f / conc) : conc;
            out[(size_t)row * NOUT + col] = (-logf(hc)) / 2.302585092994046f;
        }
    }
}

extern "C" void kernel_launch(void* const* d_in, const int* in_sizes, int n_in,
                              void* d_out, int out_size, void* d_ws, size_t ws_size,
                              hipStream_t stream) {
    const float* x = (const float*)d_in[0];
    const float* w = (const float*)d_in[1];
    float* out = (float*)d_out;

    const size_t nElem   = (size_t)BATCH * NIN;
    const size_t needWs  = nElem * 4 + nElem * 2;   // acid f32 + base bf16 = 100.7 MB
    dim3 grid(NOUT / BN, BATCH / BM);

    if (ws_size >= needWs) {
        float*          a_acid = (float*)d_ws;
        unsigned short* a_b16  = (unsigned short*)((char*)d_ws + nElem * 4);
        precompute_terms2<<<4096, 256, 0, stream>>>(x, a_acid, a_b16, (int)nElem);
        acid_gemm_hyb<<<grid, dim3(256), 0, stream>>>(a_acid, a_b16, w, out);
    } else {
        acid_gemm_fly<<<grid, dim3(256), 0, stream>>>(x, w, out);
    }
}